// Round 6
// baseline (1225.743 us; speedup 1.0000x reference)
//
#include <hip/hip_runtime.h>
#include <math.h>

// VQ-VAE quantize: z [32,8,16,16] f32, codebook [16384,8] f32
// N=8192 rows, K=16384 codes, D=8.
// Outputs (concatenated f32): z_q [65536], loss [1], idx-as-float [8192].
//
// f[n,k] = 200*dot(z_n,e_k) - 100*||e_k||^2 (softmax/argmax shift-invariant;
// T=0.01). exp underflows for f-m < -87 (validated vs fp32 ref, R2-R5).
//
// R5 lesson: per-slice local thresholds record ~40 candidates/row -> ROWCAP
// overflow -> full-K fallback for most rows (8 GB L2, 248 us). The -87
// window is tiny (~0.12 sigma) but ONLY relative to the global row max.
// Now: (1) maxpass computes exact rowmax (LDS-staged, 16 waves/CU);
// (2) candpass k-major (codes in regs, rows broadcast from LDS) records
// candidates above rowmax-87 (~3/row, exact threshold); (3) rowfix merges
// per-thread; fixup handles (never-firing) overflows wave-cooperatively.

#define KCODES 16384
#define TILE   512
#define SLICE_TILES 8          // maxpass: 4096 codes per slice
#define ROWCAP 32

__device__ __forceinline__ float dot8v(const float* zr, float4 L, float4 H,
                                       float b) {
    float a = fmaf(zr[0], L.x, b);
    a = fmaf(zr[1], L.y, a);
    a = fmaf(zr[2], L.z, a);
    a = fmaf(zr[3], L.w, a);
    a = fmaf(zr[4], H.x, a);
    a = fmaf(zr[5], H.y, a);
    a = fmaf(zr[6], H.z, a);
    a = fmaf(zr[7], H.w, a);
    return a;
}
__device__ __forceinline__ float dotv(float4 v0, float4 v1, float4 L, float4 H,
                                      float b) {
    float a = fmaf(v0.x, L.x, b);
    a = fmaf(v0.y, L.y, a);
    a = fmaf(v0.z, L.z, a);
    a = fmaf(v0.w, L.w, a);
    a = fmaf(v1.x, H.x, a);
    a = fmaf(v1.y, H.y, a);
    a = fmaf(v1.z, H.z, a);
    a = fmaf(v1.w, H.w, a);
    return a;
}
__device__ __forceinline__ float norm8(float4 L, float4 H) {
    return L.x * L.x + L.y * L.y + L.z * L.z + L.w * L.w
         + H.x * H.x + H.y * H.y + H.z * H.z + H.w * H.w;
}
// order-preserving float<->int (no NaNs here)
__device__ __forceinline__ int encf(float f) {
    int i = __float_as_int(f);
    return i < 0 ? (i ^ 0x7fffffff) : i;
}
__device__ __forceinline__ float decf(int i) {
    return __int_as_float(i < 0 ? (i ^ 0x7fffffff) : i);
}

// ---------------- maxpass: exact per-row max, K-sliced, LDS-staged --------
// 1024 blocks = 256 rowgroups(32 rows) x 4 K-slices. 36KB LDS -> 4 blk/CU.
__global__ __launch_bounds__(256, 4) void maxpass(
    const float* __restrict__ z, const float* __restrict__ cb,
    int* __restrict__ rowmax_enc)
{
    __shared__ float4 lo[2][TILE];
    __shared__ float4 hi[2][TILE];
    __shared__ float  bkt[2][TILE];

    const int tid  = threadIdx.x;
    const int wave = tid >> 6;
    const int lane = tid & 63;
    const int wrow0 = wave * 8;
    const int rowgrp = blockIdx.x >> 2;
    const int slice  = blockIdx.x & 3;
    const int growbase = rowgrp * 32;
    const int kbase = slice * (TILE * SLICE_TILES);

    float za[8][8];
#pragma unroll
    for (int r = 0; r < 8; ++r) {
        int row = growbase + wrow0 + r;
        int bb = row >> 8, hw = row & 255;
        const float* p = z + bb * 2048 + hw;
#pragma unroll
        for (int c = 0; c < 8; ++c) za[r][c] = 200.0f * p[c * 256];
    }

    const float4* cbv = (const float4*)cb;
    float4 l0, h0, l1, h1; float b0, b1;
#define STAGE_LD(t)  { int k0 = kbase + (t) * TILE + tid, k1 = k0 + 256;  \
        l0 = cbv[2 * k0]; h0 = cbv[2 * k0 + 1];                           \
        l1 = cbv[2 * k1]; h1 = cbv[2 * k1 + 1];                           \
        b0 = -100.0f * norm8(l0, h0); b1 = -100.0f * norm8(l1, h1); }
#define STAGE_WR(bf) { lo[bf][tid] = l0; hi[bf][tid] = h0;                \
        lo[bf][tid + 256] = l1; hi[bf][tid + 256] = h1;                   \
        bkt[bf][tid] = b0; bkt[bf][tid + 256] = b1; }

    STAGE_LD(0); STAGE_WR(0);
    __syncthreads();

    float wm[8];
#pragma unroll
    for (int r = 0; r < 8; ++r) wm[r] = -3.4e38f;

    for (int t = 0; t < SLICE_TILES; ++t) {
        const int bf = t & 1;
        const bool more = (t + 1 < SLICE_TILES);
        if (more) STAGE_LD(t + 1);
#pragma unroll 2
        for (int j = 0; j < 8; ++j) {
            int ci = j * 64 + lane;
            float4 L = lo[bf][ci], H = hi[bf][ci];
            float b = bkt[bf][ci];
#pragma unroll
            for (int r = 0; r < 8; ++r)
                wm[r] = fmaxf(wm[r], dot8v(za[r], L, H, b));
        }
        if (more) STAGE_WR((t + 1) & 1);
        __syncthreads();
    }
#undef STAGE_LD
#undef STAGE_WR

#pragma unroll
    for (int r = 0; r < 8; ++r) {
        float m = wm[r];
#pragma unroll
        for (int off = 32; off; off >>= 1) m = fmaxf(m, __shfl_xor(m, off));
        if (lane == 0) atomicMax(&rowmax_enc[growbase + wrow0 + r], encf(m));
    }
}

// ---------------- candpass: k-major, record candidates above rowmax-87 ----
// 1024 blocks = 32 rowgroups(256 rows) x 32 kgroups(512 codes). Codes in
// registers (2/thread); rows broadcast from LDS (3 reads per 128 pairs).
__global__ __launch_bounds__(256, 4) void candpass(
    const float* __restrict__ z, const float* __restrict__ cb,
    const int* __restrict__ rowmax_enc, int* __restrict__ gcnt,
    float2* __restrict__ grec)
{
    __shared__ float lz[256 * 8];    // 8KB, rows pre-scaled by 200
    __shared__ float lthr[256];      // rowmax - 87

    const int tid = threadIdx.x;
    const int rowgrp = blockIdx.x >> 5;      // 0..31, == batch b
    const int kgrp   = blockIdx.x & 31;
    const int row0 = rowgrp * 256;

    {   // stage 256 rows (coalesced per dim) + thresholds
        const float* zp = z + rowgrp * 2048 + tid;
#pragma unroll
        for (int c = 0; c < 8; ++c) lz[tid * 8 + c] = 200.0f * zp[c * 256];
        lthr[tid] = decf(rowmax_enc[row0 + tid]) - 87.0f;
    }
    __syncthreads();

    const float4* cbv = (const float4*)cb;
    const int k0 = kgrp * 512 + tid, k1 = k0 + 256;
    float4 A0 = cbv[2 * k0], A1 = cbv[2 * k0 + 1];
    float4 B0 = cbv[2 * k1], B1 = cbv[2 * k1 + 1];
    const float ba = -100.0f * norm8(A0, A1);
    const float bb = -100.0f * norm8(B0, B1);

    const float4* lz4 = (const float4*)lz;
#pragma unroll 4
    for (int n = 0; n < 256; ++n) {
        float4 v0 = lz4[2 * n], v1 = lz4[2 * n + 1];   // broadcast
        float thr = lthr[n];
        float f0 = dotv(v0, v1, A0, A1, ba);
        float f1 = dotv(v0, v1, B0, B1, bb);
        bool h0 = f0 > thr, h1 = f1 > thr;
        if (__any(h0 || h1)) {                          // rare (~3/row total)
            int row = row0 + n;
            if (h0) {
                int pos = atomicAdd(&gcnt[row], 1);
                if (pos < ROWCAP)
                    grec[row * ROWCAP + pos] = make_float2(f0, __int_as_float(k0));
            }
            if (h1) {
                int pos = atomicAdd(&gcnt[row], 1);
                if (pos < ROWCAP)
                    grec[row * ROWCAP + pos] = make_float2(f1, __int_as_float(k1));
            }
        }
    }
}

// ---------------- rowfix: 1 thread/row, merge ~3 candidates ----------------
__global__ __launch_bounds__(256) void rowfix(
    const float* __restrict__ z, const float* __restrict__ cb,
    const int* __restrict__ gcnt, const float2* __restrict__ grec,
    float* __restrict__ avgp, float* __restrict__ out_zq,
    float* __restrict__ out_idx, float* __restrict__ scal)
{
    const int row = blockIdx.x * 256 + threadIdx.x;
    const int lane = threadIdx.x & 63;
    const float4* cbv = (const float4*)cb;
    const int c = gcnt[row];

    float ent = 0.0f, sq = 0.0f;
    if (c <= ROWCAP) {             // overflow rows handled by fixup
        const float2* rp = grec + row * ROWCAP;
        float m = -3.4e38f;
        for (int i = 0; i < c; ++i) m = fmaxf(m, rp[i].x);   // true max (recorded)
        float s = 0.0f, t = 0.0f;
        int kmin = 0x7fffffff;
        for (int i = 0; i < c; ++i) {
            float2 rc = rp[i];
            float x = rc.x - m;
            float e = __expf(x);
            s += e; t = fmaf(x, e, t);
            if (x == 0.0f) kmin = min(kmin, __float_as_int(rc.y));
        }
        float rs = 1.0f / s;
        for (int i = 0; i < c; ++i) {
            float2 rc = rp[i];
            atomicAdd(&avgp[__float_as_int(rc.y)], __expf(rc.x - m) * rs);
        }
        ent = t * rs - logf(s);
        out_idx[row] = (float)kmin;
        float4 q0 = cbv[2 * kmin], q1 = cbv[2 * kmin + 1];
        float qv[8] = {q0.x, q0.y, q0.z, q0.w, q1.x, q1.y, q1.z, q1.w};
        int bbr = row >> 8, hw = row & 255;
        const float* zp = z + bbr * 2048 + hw;
        float* o = out_zq + bbr * 2048 + hw;
#pragma unroll
        for (int ch = 0; ch < 8; ++ch) {
            float raw = zp[ch * 256];
            o[ch * 256] = qv[ch];     // coalesced across threads
            float dq = qv[ch] - raw;
            sq += dq * dq;
        }
    }
#pragma unroll
    for (int off = 32; off; off >>= 1) {
        sq  += __shfl_xor(sq, off);
        ent += __shfl_xor(ent, off);
    }
    if (lane == 0) {
        atomicAdd(&scal[0], sq);
        atomicAdd(&scal[1], ent);
    }
}

// ---------------- fixup: exact recompute for overflowed rows (rare) --------
__global__ __launch_bounds__(256) void fixup(
    const float* __restrict__ z, const float* __restrict__ cb,
    const int* __restrict__ gcnt, float* __restrict__ avgp,
    float* __restrict__ out_zq, float* __restrict__ out_idx,
    float* __restrict__ scal)
{
    const int wave = threadIdx.x >> 6;
    const int lane = threadIdx.x & 63;
    const int rowbase = blockIdx.x * 256 + wave * 64;
    const float4* cbv = (const float4*)cb;

    bool over = gcnt[rowbase + lane] > ROWCAP;
    unsigned long long mask = __ballot(over);
    float entW = 0.0f, sqW = 0.0f;
    bool did = false;

    while (mask) {
        int bit = __ffsll((long long)mask) - 1;
        mask &= mask - 1;
        int rowg = rowbase + bit;
        did = true;
        float zs[8], zraw[8];
        int bbr = rowg >> 8, hw = rowg & 255;
        const float* zp = z + bbr * 2048 + hw;
#pragma unroll
        for (int ch = 0; ch < 8; ++ch) {
            zraw[ch] = zp[ch * 256];
            zs[ch] = 200.0f * zraw[ch];
        }
        float m = -3.4e38f, s = 0.0f, t = 0.0f;
        int kloc = 0x7fffffff;
        for (int k = lane; k < KCODES; k += 64) {
            float4 L = cbv[2 * k], H = cbv[2 * k + 1];
            float f = dot8v(zs, L, H, -100.0f * norm8(L, H));
            float x = f - m;
            if (x > 0.0f) {
                float fsc = __expf(-x);
                t = fsc * fmaf(-x, s, t);
                s = fmaf(s, fsc, 1.0f);
                m = f; kloc = k;
            } else if (x > -87.0f) {
                float e = __expf(x);
                s += e; t = fmaf(x, e, t);
            }
        }
        for (int off = 32; off; off >>= 1) {
            float mo = __shfl_xor(m, off);
            float so = __shfl_xor(s, off);
            float to = __shfl_xor(t, off);
            int   ko = __shfl_xor(kloc, off);
            float mn = fmaxf(m, mo);
            float d1 = m - mn, d2 = mo - mn;
            float f1 = __expf(d1), f2 = __expf(d2);
            t = f1 * fmaf(d1, s, t) + f2 * fmaf(d2, so, to);
            s = f1 * s + f2 * so;
            kloc = (m > mo) ? kloc : ((mo > m) ? ko : (kloc < ko ? kloc : ko));
            m = mn;
        }
        float rs = 1.0f / s;
        for (int k = lane; k < KCODES; k += 64) {
            float4 L = cbv[2 * k], H = cbv[2 * k + 1];
            float f = dot8v(zs, L, H, -100.0f * norm8(L, H));
            float x = f - m;
            if (x > -87.0f) atomicAdd(&avgp[k], __expf(x) * rs);
        }
        if (lane == 0) {
            entW += t * rs - logf(s);
            out_idx[rowg] = (float)kloc;
            float4 q0 = cbv[2 * kloc], q1 = cbv[2 * kloc + 1];
            float qv[8] = {q0.x, q0.y, q0.z, q0.w, q1.x, q1.y, q1.z, q1.w};
            float* o = out_zq + bbr * 2048 + hw;
#pragma unroll
            for (int ch = 0; ch < 8; ++ch) {
                o[ch * 256] = qv[ch];
                float dq = qv[ch] - zraw[ch];
                sqW += dq * dq;
            }
        }
    }
    if (did && lane == 0) {
        atomicAdd(&scal[0], sqW);
        atomicAdd(&scal[1], entW);
    }
}

// ---------------- finalize: avg entropy + loss assembly ----------------
__global__ __launch_bounds__(256) void finalize(
    const float* __restrict__ avgp, const float* __restrict__ scal,
    float* __restrict__ out_loss)
{
    float acc = 0.0f;
    for (int k = threadIdx.x; k < KCODES; k += 256) {
        float avg = avgp[k] * (1.0f / 8192.0f);
        acc += avg * logf(avg + 1e-5f);    // avg==0 contributes exactly 0
    }
#pragma unroll
    for (int off = 32; off > 0; off >>= 1) acc += __shfl_xor(acc, off);
    __shared__ float red[4];
    int wave = threadIdx.x >> 6, lane = threadIdx.x & 63;
    if (lane == 0) red[wave] = acc;
    __syncthreads();
    if (threadIdx.x == 0) {
        float T = red[0] + red[1] + red[2] + red[3];   // sum avg*log(avg+eps)
        // loss = 1.25*mean((zq-z)^2) + 0.1*(sample_entropy - avg_entropy)
        float loss = 1.25f * (scal[0] * (1.0f / 65536.0f))
                   + 0.1f * (T - scal[1] * (1.0f / 8192.0f));
        out_loss[0] = loss;
    }
}

extern "C" void kernel_launch(void* const* d_in, const int* in_sizes, int n_in,
                              void* d_out, int out_size, void* d_ws, size_t ws_size,
                              hipStream_t stream) {
    const float* z  = (const float*)d_in[0];   // [32,8,16,16]
    const float* cb = (const float*)d_in[1];   // [16384,8]
    float* out = (float*)d_out;
    float* ws  = (float*)d_ws;

    // workspace layout (floats)
    float*  avgp = ws;                        // 16384 : sum_n p[n,k]
    float*  scal = ws + 16384;                // 2 (+6 pad)
    int*    gcnt = (int*)(ws + 16392);        // 8192  : per-row cand count
    int*    rmax = (int*)(ws + 24584);        // 8192  : encoded row max
    float2* grec = (float2*)(ws + 32776);     // 8192*32 float2 = 2 MB

    float* out_zq   = out;           // 65536
    float* out_loss = out + 65536;   // 1
    float* out_idx  = out + 65537;   // 8192

    // zero avgp/scal/gcnt; rowmax <- 0x80808080 (decodes ~ -2.5e38)
    hipMemsetAsync(ws, 0, (16384 + 8 + 8192) * sizeof(float), stream);
    hipMemsetAsync(rmax, 0x80, 8192 * sizeof(int), stream);

    maxpass <<<1024, 256, 0, stream>>>(z, cb, rmax);
    candpass<<<1024, 256, 0, stream>>>(z, cb, rmax, gcnt, grec);
    rowfix  <<<32,   256, 0, stream>>>(z, cb, gcnt, grec, avgp, out_zq,
                                       out_idx, scal);
    fixup   <<<32,   256, 0, stream>>>(z, cb, gcnt, avgp, out_zq, out_idx, scal);
    finalize<<<1,    256, 0, stream>>>(avgp, scal, out_loss);
}

// Round 7
// 340.992 us; speedup vs baseline: 3.5946x; 3.5946x over previous
//
#include <hip/hip_runtime.h>
#include <math.h>

// VQ-VAE quantize: z [32,8,16,16] f32, codebook [16384,8] f32
// N=8192 rows, K=16384 codes, D=8.
// Outputs (concatenated f32): z_q [65536], loss [1], idx-as-float [8192].
//
// f[n,k] = 200*dot(z_n,e_k) - 100*||e_k||^2 (softmax/argmax shift-invariant;
// T=0.01). exp underflows for f-m < -87 (validated vs fp32 ref, R2-R6).
//
// R6 lesson: candidates/row ~10-30 with fat tail (8-dim: P(d<t) ~ t^4), so
// ROWCAP=32 overflowed often and the 32-block serial fixup cost 1084 us.
// Now ROWCAP=64 (1 cand/lane), rowfix is wave-per-row with the exact full-K
// fallback merged in (wave-cooperative, 8192-way parallel when it fires).

#define KCODES 16384
#define TILE   512
#define SLICE_TILES 8          // maxpass: 4096 codes per slice
#define ROWCAP 64

__device__ __forceinline__ float dot8v(const float* zr, float4 L, float4 H,
                                       float b) {
    float a = fmaf(zr[0], L.x, b);
    a = fmaf(zr[1], L.y, a);
    a = fmaf(zr[2], L.z, a);
    a = fmaf(zr[3], L.w, a);
    a = fmaf(zr[4], H.x, a);
    a = fmaf(zr[5], H.y, a);
    a = fmaf(zr[6], H.z, a);
    a = fmaf(zr[7], H.w, a);
    return a;
}
__device__ __forceinline__ float dotv(float4 v0, float4 v1, float4 L, float4 H,
                                      float b) {
    float a = fmaf(v0.x, L.x, b);
    a = fmaf(v0.y, L.y, a);
    a = fmaf(v0.z, L.z, a);
    a = fmaf(v0.w, L.w, a);
    a = fmaf(v1.x, H.x, a);
    a = fmaf(v1.y, H.y, a);
    a = fmaf(v1.z, H.z, a);
    a = fmaf(v1.w, H.w, a);
    return a;
}
__device__ __forceinline__ float norm8(float4 L, float4 H) {
    return L.x * L.x + L.y * L.y + L.z * L.z + L.w * L.w
         + H.x * H.x + H.y * H.y + H.z * H.z + H.w * H.w;
}
// order-preserving float<->int (no NaNs here)
__device__ __forceinline__ int encf(float f) {
    int i = __float_as_int(f);
    return i < 0 ? (i ^ 0x7fffffff) : i;
}
__device__ __forceinline__ float decf(int i) {
    return __int_as_float(i < 0 ? (i ^ 0x7fffffff) : i);
}

// ---------------- maxpass: exact per-row max, K-sliced, LDS-staged --------
// 1024 blocks = 256 rowgroups(32 rows) x 4 K-slices. 36KB LDS -> 4 blk/CU.
__global__ __launch_bounds__(256, 4) void maxpass(
    const float* __restrict__ z, const float* __restrict__ cb,
    int* __restrict__ rowmax_enc)
{
    __shared__ float4 lo[2][TILE];
    __shared__ float4 hi[2][TILE];
    __shared__ float  bkt[2][TILE];

    const int tid  = threadIdx.x;
    const int wave = tid >> 6;
    const int lane = tid & 63;
    const int wrow0 = wave * 8;
    const int rowgrp = blockIdx.x >> 2;
    const int slice  = blockIdx.x & 3;
    const int growbase = rowgrp * 32;
    const int kbase = slice * (TILE * SLICE_TILES);

    float za[8][8];
#pragma unroll
    for (int r = 0; r < 8; ++r) {
        int row = growbase + wrow0 + r;
        int bb = row >> 8, hw = row & 255;
        const float* p = z + bb * 2048 + hw;
#pragma unroll
        for (int c = 0; c < 8; ++c) za[r][c] = 200.0f * p[c * 256];
    }

    const float4* cbv = (const float4*)cb;
    float4 l0, h0, l1, h1; float b0, b1;
#define STAGE_LD(t)  { int k0 = kbase + (t) * TILE + tid, k1 = k0 + 256;  \
        l0 = cbv[2 * k0]; h0 = cbv[2 * k0 + 1];                           \
        l1 = cbv[2 * k1]; h1 = cbv[2 * k1 + 1];                           \
        b0 = -100.0f * norm8(l0, h0); b1 = -100.0f * norm8(l1, h1); }
#define STAGE_WR(bf) { lo[bf][tid] = l0; hi[bf][tid] = h0;                \
        lo[bf][tid + 256] = l1; hi[bf][tid + 256] = h1;                   \
        bkt[bf][tid] = b0; bkt[bf][tid + 256] = b1; }

    STAGE_LD(0); STAGE_WR(0);
    __syncthreads();

    float wm[8];
#pragma unroll
    for (int r = 0; r < 8; ++r) wm[r] = -3.4e38f;

    for (int t = 0; t < SLICE_TILES; ++t) {
        const int bf = t & 1;
        const bool more = (t + 1 < SLICE_TILES);
        if (more) STAGE_LD(t + 1);
#pragma unroll 2
        for (int j = 0; j < 8; ++j) {
            int ci = j * 64 + lane;
            float4 L = lo[bf][ci], H = hi[bf][ci];
            float b = bkt[bf][ci];
#pragma unroll
            for (int r = 0; r < 8; ++r)
                wm[r] = fmaxf(wm[r], dot8v(za[r], L, H, b));
        }
        if (more) STAGE_WR((t + 1) & 1);
        __syncthreads();
    }
#undef STAGE_LD
#undef STAGE_WR

#pragma unroll
    for (int r = 0; r < 8; ++r) {
        float m = wm[r];
#pragma unroll
        for (int off = 32; off; off >>= 1) m = fmaxf(m, __shfl_xor(m, off));
        if (lane == 0) atomicMax(&rowmax_enc[growbase + wrow0 + r], encf(m));
    }
}

// ---------------- candpass: k-major, record candidates above rowmax-87 ----
// 1024 blocks = 32 rowgroups(256 rows) x 32 kgroups(512 codes). Codes in
// registers (2/thread); rows broadcast from LDS.
__global__ __launch_bounds__(256, 4) void candpass(
    const float* __restrict__ z, const float* __restrict__ cb,
    const int* __restrict__ rowmax_enc, int* __restrict__ gcnt,
    float2* __restrict__ grec)
{
    __shared__ float lz[256 * 8];    // 8KB, rows pre-scaled by 200
    __shared__ float lthr[256];      // rowmax - 87

    const int tid = threadIdx.x;
    const int rowgrp = blockIdx.x >> 5;      // 0..31, == batch b
    const int kgrp   = blockIdx.x & 31;
    const int row0 = rowgrp * 256;

    {   // stage 256 rows (coalesced per dim) + thresholds
        const float* zp = z + rowgrp * 2048 + tid;
#pragma unroll
        for (int c = 0; c < 8; ++c) lz[tid * 8 + c] = 200.0f * zp[c * 256];
        lthr[tid] = decf(rowmax_enc[row0 + tid]) - 87.0f;
    }
    __syncthreads();

    const float4* cbv = (const float4*)cb;
    const int k0 = kgrp * 512 + tid, k1 = k0 + 256;
    float4 A0 = cbv[2 * k0], A1 = cbv[2 * k0 + 1];
    float4 B0 = cbv[2 * k1], B1 = cbv[2 * k1 + 1];
    const float ba = -100.0f * norm8(A0, A1);
    const float bb = -100.0f * norm8(B0, B1);

    const float4* lz4 = (const float4*)lz;
#pragma unroll 4
    for (int n = 0; n < 256; ++n) {
        float4 v0 = lz4[2 * n], v1 = lz4[2 * n + 1];   // broadcast
        float thr = lthr[n];
        float f0 = dotv(v0, v1, A0, A1, ba);
        float f1 = dotv(v0, v1, B0, B1, bb);
        bool h0 = f0 > thr, h1 = f1 > thr;
        if (__any(h0 || h1)) {                          // rare
            int row = row0 + n;
            if (h0) {
                int pos = atomicAdd(&gcnt[row], 1);
                if (pos < ROWCAP)
                    grec[row * ROWCAP + pos] = make_float2(f0, __int_as_float(k0));
            }
            if (h1) {
                int pos = atomicAdd(&gcnt[row], 1);
                if (pos < ROWCAP)
                    grec[row * ROWCAP + pos] = make_float2(f1, __int_as_float(k1));
            }
        }
    }
}

// ---------------- rowfix: 1 wave/row; merged exact fallback ----------------
// 2048 blocks x 4 waves. Fast path: lane i holds candidate i (<=64), butterfly
// reduce. Overflow (>64, ~never): wave-cooperative exact full-K recompute.
__global__ __launch_bounds__(256) void rowfix(
    const float* __restrict__ z, const float* __restrict__ cb,
    const int* __restrict__ gcnt, const float2* __restrict__ grec,
    float* __restrict__ avgp, float* __restrict__ out_zq,
    float* __restrict__ out_idx, float* __restrict__ scal)
{
    const int wave = threadIdx.x >> 6;
    const int lane = threadIdx.x & 63;
    const int row = blockIdx.x * 4 + wave;
    const float4* cbv = (const float4*)cb;
    const int c = gcnt[row];
    const int bbr = row >> 8, hw = row & 255;

    float ent = 0.0f, sq = 0.0f;   // lane-0 carries per-row scalars
    if (c <= ROWCAP) {
        float f = -3.4e38f; int k = 0x7fffffff;
        if (lane < c) {
            float2 rc = grec[row * ROWCAP + lane];   // coalesced
            f = rc.x; k = __float_as_int(rc.y);
        }
        float m = f;
#pragma unroll
        for (int off = 32; off; off >>= 1) m = fmaxf(m, __shfl_xor(m, off));
        float x = f - m;
        float e = 0.0f, t = 0.0f;
        int kmin = 0x7fffffff;
        if (lane < c) {
            e = __expf(x);            // x > -87 guaranteed (thr = m-87)
            t = x * e;
            if (x == 0.0f) kmin = k;
        }
        float s = e;
#pragma unroll
        for (int off = 32; off; off >>= 1) {
            s += __shfl_xor(s, off);
            t += __shfl_xor(t, off);
            kmin = min(kmin, __shfl_xor(kmin, off));
        }
        float rs = 1.0f / s;
        if (e != 0.0f) atomicAdd(&avgp[k], e * rs);
        if (lane == 0) {
            ent = t * rs - logf(s);
            out_idx[row] = (float)kmin;
            float4 q0 = cbv[2 * kmin], q1 = cbv[2 * kmin + 1];
            float qv[8] = {q0.x, q0.y, q0.z, q0.w, q1.x, q1.y, q1.z, q1.w};
            const float* zp = z + bbr * 2048 + hw;
            float* o = out_zq + bbr * 2048 + hw;
#pragma unroll
            for (int ch = 0; ch < 8; ++ch) {
                float raw = zp[ch * 256];
                o[ch * 256] = qv[ch];
                float dq = qv[ch] - raw;
                sq += dq * dq;
            }
        }
    } else {
        // overflow fallback: exact wave-parallel recompute (rare)
        float zs[8], zraw[8];
        const float* zp = z + bbr * 2048 + hw;
#pragma unroll
        for (int ch = 0; ch < 8; ++ch) {
            zraw[ch] = zp[ch * 256];
            zs[ch] = 200.0f * zraw[ch];
        }
        float m = -3.4e38f, s = 0.0f, t = 0.0f;
        int kloc = 0x7fffffff;
        for (int k = lane; k < KCODES; k += 64) {
            float4 L = cbv[2 * k], H = cbv[2 * k + 1];
            float f = dot8v(zs, L, H, -100.0f * norm8(L, H));
            float x = f - m;
            if (x > 0.0f) {
                float fsc = __expf(-x);
                t = fsc * fmaf(-x, s, t);
                s = fmaf(s, fsc, 1.0f);
                m = f; kloc = k;
            } else if (x > -87.0f) {
                float e = __expf(x);
                s += e; t = fmaf(x, e, t);
            }
        }
        for (int off = 32; off; off >>= 1) {
            float mo = __shfl_xor(m, off);
            float so = __shfl_xor(s, off);
            float to = __shfl_xor(t, off);
            int   ko = __shfl_xor(kloc, off);
            float mn = fmaxf(m, mo);
            float d1 = m - mn, d2 = mo - mn;
            float f1 = __expf(d1), f2 = __expf(d2);
            t = f1 * fmaf(d1, s, t) + f2 * fmaf(d2, so, to);
            s = f1 * s + f2 * so;
            kloc = (m > mo) ? kloc : ((mo > m) ? ko : (kloc < ko ? kloc : ko));
            m = mn;
        }
        float rs = 1.0f / s;
        for (int k = lane; k < KCODES; k += 64) {
            float4 L = cbv[2 * k], H = cbv[2 * k + 1];
            float f = dot8v(zs, L, H, -100.0f * norm8(L, H));
            float x = f - m;
            if (x > -87.0f) atomicAdd(&avgp[k], __expf(x) * rs);
        }
        if (lane == 0) {
            ent = t * rs - logf(s);
            out_idx[row] = (float)kloc;
            float4 q0 = cbv[2 * kloc], q1 = cbv[2 * kloc + 1];
            float qv[8] = {q0.x, q0.y, q0.z, q0.w, q1.x, q1.y, q1.z, q1.w};
            float* o = out_zq + bbr * 2048 + hw;
#pragma unroll
            for (int ch = 0; ch < 8; ++ch) {
                o[ch * 256] = qv[ch];
                float dq = qv[ch] - zraw[ch];
                sq += dq * dq;
            }
        }
    }
    // block reduce (4 per-row scalars) -> 2 atomics per block
    __shared__ float redSq[4], redEnt[4];
    if (lane == 0) { redSq[wave] = sq; redEnt[wave] = ent; }
    __syncthreads();
    if (threadIdx.x == 0) {
        atomicAdd(&scal[0], redSq[0] + redSq[1] + redSq[2] + redSq[3]);
        atomicAdd(&scal[1], redEnt[0] + redEnt[1] + redEnt[2] + redEnt[3]);
    }
}

// ---------------- finalize: avg entropy + loss assembly ----------------
__global__ __launch_bounds__(256) void finalize(
    const float* __restrict__ avgp, const float* __restrict__ scal,
    float* __restrict__ out_loss)
{
    float acc = 0.0f;
    for (int k = threadIdx.x; k < KCODES; k += 256) {
        float avg = avgp[k] * (1.0f / 8192.0f);
        acc += avg * logf(avg + 1e-5f);    // avg==0 contributes exactly 0
    }
#pragma unroll
    for (int off = 32; off > 0; off >>= 1) acc += __shfl_xor(acc, off);
    __shared__ float red[4];
    int wave = threadIdx.x >> 6, lane = threadIdx.x & 63;
    if (lane == 0) red[wave] = acc;
    __syncthreads();
    if (threadIdx.x == 0) {
        float T = red[0] + red[1] + red[2] + red[3];   // sum avg*log(avg+eps)
        // loss = 1.25*mean((zq-z)^2) + 0.1*(sample_entropy - avg_entropy)
        float loss = 1.25f * (scal[0] * (1.0f / 65536.0f))
                   + 0.1f * (T - scal[1] * (1.0f / 8192.0f));
        out_loss[0] = loss;
    }
}

extern "C" void kernel_launch(void* const* d_in, const int* in_sizes, int n_in,
                              void* d_out, int out_size, void* d_ws, size_t ws_size,
                              hipStream_t stream) {
    const float* z  = (const float*)d_in[0];   // [32,8,16,16]
    const float* cb = (const float*)d_in[1];   // [16384,8]
    float* out = (float*)d_out;
    float* ws  = (float*)d_ws;

    // workspace layout (floats)
    float*  avgp = ws;                        // 16384 : sum_n p[n,k]
    float*  scal = ws + 16384;                // 2 (+6 pad)
    int*    gcnt = (int*)(ws + 16392);        // 8192  : per-row cand count
    int*    rmax = (int*)(ws + 24584);        // 8192  : encoded row max
    float2* grec = (float2*)(ws + 32776);     // 8192*64 float2 = 4 MB

    float* out_zq   = out;           // 65536
    float* out_loss = out + 65536;   // 1
    float* out_idx  = out + 65537;   // 8192

    // zero avgp/scal/gcnt; rowmax <- 0x80808080 (decodes ~ -2.5e38)
    hipMemsetAsync(ws, 0, (16384 + 8 + 8192) * sizeof(float), stream);
    hipMemsetAsync(rmax, 0x80, 8192 * sizeof(int), stream);

    maxpass <<<1024, 256, 0, stream>>>(z, cb, rmax);
    candpass<<<1024, 256, 0, stream>>>(z, cb, rmax, gcnt, grec);
    rowfix  <<<2048, 256, 0, stream>>>(z, cb, gcnt, grec, avgp, out_zq,
                                       out_idx, scal);
    finalize<<<1,    256, 0, stream>>>(avgp, scal, out_loss);
}

// Round 8
// 261.173 us; speedup vs baseline: 4.6932x; 1.3056x over previous
//
#include <hip/hip_runtime.h>
#include <math.h>

// VQ-VAE quantize: z [32,8,16,16] f32, codebook [16384,8] f32
// N=8192 rows, K=16384 codes, D=8.
// Outputs (concatenated f32): z_q [65536], loss [1], idx-as-float [8192].
//
// f[n,k] = 200*dot(z_n,e_k) - 100*||e_k||^2 (softmax/argmax shift-invariant;
// T=0.01). exp underflows for f-m < -87 (validated vs fp32 ref, R2-R7).
//
// R7 lesson: wave-serial overflow fallback inside rowfix = ~64us per
// overflowed row; a handful of fat-tail rows (>64 candidates) defined the
// 196us kernel. Now overflow rows go to a compacted list handled by a
// block-cooperative kernel (~2-3us/row, parallel). maxpass uses async
// global_load_lds staging; candpass holds 4 codes/thread to halve LDS load.

#define KCODES 16384
#define TILE   512
#define SLICE_TILES 8          // maxpass: 4096 codes per slice
#define ROWCAP 64

#define ASYNC_CP16(lds, gl) __builtin_amdgcn_global_load_lds( \
    (const __attribute__((address_space(1))) unsigned int*)(gl), \
    (__attribute__((address_space(3))) unsigned int*)(lds), 16, 0, 0)
#define ASYNC_CP4(lds, gl) __builtin_amdgcn_global_load_lds( \
    (const __attribute__((address_space(1))) unsigned int*)(gl), \
    (__attribute__((address_space(3))) unsigned int*)(lds), 4, 0, 0)

__device__ __forceinline__ float dot8v(const float* zr, float4 L, float4 H,
                                       float b) {
    float a = fmaf(zr[0], L.x, b);
    a = fmaf(zr[1], L.y, a);
    a = fmaf(zr[2], L.z, a);
    a = fmaf(zr[3], L.w, a);
    a = fmaf(zr[4], H.x, a);
    a = fmaf(zr[5], H.y, a);
    a = fmaf(zr[6], H.z, a);
    a = fmaf(zr[7], H.w, a);
    return a;
}
__device__ __forceinline__ float dotv(float4 v0, float4 v1, float4 L, float4 H,
                                      float b) {
    float a = fmaf(v0.x, L.x, b);
    a = fmaf(v0.y, L.y, a);
    a = fmaf(v0.z, L.z, a);
    a = fmaf(v0.w, L.w, a);
    a = fmaf(v1.x, H.x, a);
    a = fmaf(v1.y, H.y, a);
    a = fmaf(v1.z, H.z, a);
    a = fmaf(v1.w, H.w, a);
    return a;
}
__device__ __forceinline__ float norm8(float4 L, float4 H) {
    return L.x * L.x + L.y * L.y + L.z * L.z + L.w * L.w
         + H.x * H.x + H.y * H.y + H.z * H.z + H.w * H.w;
}
// order-preserving float<->int (no NaNs here)
__device__ __forceinline__ int encf(float f) {
    int i = __float_as_int(f);
    return i < 0 ? (i ^ 0x7fffffff) : i;
}
__device__ __forceinline__ float decf(int i) {
    return __int_as_float(i < 0 ? (i ^ 0x7fffffff) : i);
}

// ---------------- prep: codebook norms ----------------
__global__ __launch_bounds__(256) void prep_cb(const float* __restrict__ cb,
                                               float* __restrict__ bk) {
    int k = blockIdx.x * 256 + threadIdx.x;
    const float4* c4 = (const float4*)cb;
    bk[k] = -100.0f * norm8(c4[2 * k], c4[2 * k + 1]);
}

// ---------------- maxpass: exact per-row max, K-sliced, async LDS ---------
// 1024 blocks = 256 rowgroups(32 rows) x 4 K-slices. 36KB LDS -> 4 blk/CU.
__global__ __launch_bounds__(256, 4) void maxpass(
    const float* __restrict__ z, const float* __restrict__ cb,
    const float* __restrict__ bkg, int* __restrict__ rowmax_enc)
{
    __shared__ float4 cbt[2][2 * TILE];   // interleaved lo/hi, 2 x 16KB
    __shared__ float  bkt[2][TILE];       // 2 x 2KB

    const int tid  = threadIdx.x;
    const int wave = tid >> 6;
    const int lane = tid & 63;
    const int wrow0 = wave * 8;
    const int rowgrp = blockIdx.x >> 2;
    const int slice  = blockIdx.x & 3;
    const int growbase = rowgrp * 32;
    const int kbase = slice * (TILE * SLICE_TILES);

    float za[8][8];
#pragma unroll
    for (int r = 0; r < 8; ++r) {
        int row = growbase + wrow0 + r;
        int bb = row >> 8, hw = row & 255;
        const float* p = z + bb * 2048 + hw;
#pragma unroll
        for (int c = 0; c < 8; ++c) za[r][c] = 200.0f * p[c * 256];
    }

    const float4* cbv = (const float4*)cb;
#define STAGE(t, bf) { \
        const float4* src = cbv + (size_t)(kbase + (t) * TILE) * 2;       \
        _Pragma("unroll")                                                 \
        for (int j = 0; j < 4; ++j)                                       \
            ASYNC_CP16(&cbt[bf][j * 256 + tid], src + j * 256 + tid);     \
        const float* bs = bkg + kbase + (t) * TILE;                       \
        _Pragma("unroll")                                                 \
        for (int j = 0; j < 2; ++j)                                       \
            ASYNC_CP4(&bkt[bf][j * 256 + tid], bs + j * 256 + tid); }

    STAGE(0, 0);
    __syncthreads();    // vmcnt(0) drain: tile 0 landed

    float wm[8];
#pragma unroll
    for (int r = 0; r < 8; ++r) wm[r] = -3.4e38f;

    for (int t = 0; t < SLICE_TILES; ++t) {
        const int bf = t & 1;
        if (t + 1 < SLICE_TILES) STAGE(t + 1, (t + 1) & 1);
#pragma unroll 2
        for (int j = 0; j < 8; ++j) {
            int ci = j * 64 + lane;
            float4 L = cbt[bf][2 * ci], H = cbt[bf][2 * ci + 1];
            float b = bkt[bf][ci];
#pragma unroll
            for (int r = 0; r < 8; ++r)
                wm[r] = fmaxf(wm[r], dot8v(za[r], L, H, b));
        }
        __syncthreads();   // next tile's async loads drained here
    }
#undef STAGE

#pragma unroll
    for (int r = 0; r < 8; ++r) {
        float m = wm[r];
#pragma unroll
        for (int off = 32; off; off >>= 1) m = fmaxf(m, __shfl_xor(m, off));
        if (lane == 0) atomicMax(&rowmax_enc[growbase + wrow0 + r], encf(m));
    }
}

// ---------------- candpass: k-major, 4 codes/thread -----------------------
// 1024 blocks = 64 rowgroups(128 rows) x 16 kgroups(1024 codes).
__global__ __launch_bounds__(256, 4) void candpass(
    const float* __restrict__ z, const float* __restrict__ cb,
    const int* __restrict__ rowmax_enc, int* __restrict__ gcnt,
    float2* __restrict__ grec)
{
    __shared__ float lz[128 * 8];    // 4KB, rows pre-scaled by 200
    __shared__ float lthr[128];      // rowmax - 87

    const int tid = threadIdx.x;
    const int rowgrp = blockIdx.x >> 4;      // 0..63
    const int kgrp   = blockIdx.x & 15;
    const int row0 = rowgrp * 128;

    {   // stage 128 rows (coalesced per dim, threads split c-range)
        int rh = tid & 127;
        const float* zp = z + (rowgrp >> 1) * 2048 + (rowgrp & 1) * 128 + rh;
        if (tid < 128) {
#pragma unroll
            for (int c = 0; c < 4; ++c) lz[rh * 8 + c] = 200.0f * zp[c * 256];
            lthr[rh] = decf(rowmax_enc[row0 + rh]) - 87.0f;
        } else {
#pragma unroll
            for (int c = 4; c < 8; ++c) lz[rh * 8 + c] = 200.0f * zp[c * 256];
        }
    }
    __syncthreads();

    const float4* cbv = (const float4*)cb;
    const int k0 = kgrp * 1024 + tid;
    float4 A0 = cbv[2 * k0], A1 = cbv[2 * k0 + 1];
    float4 B0 = cbv[2 * (k0 + 256)], B1 = cbv[2 * (k0 + 256) + 1];
    float4 C0 = cbv[2 * (k0 + 512)], C1 = cbv[2 * (k0 + 512) + 1];
    float4 D0 = cbv[2 * (k0 + 768)], D1 = cbv[2 * (k0 + 768) + 1];
    const float na = -100.0f * norm8(A0, A1);
    const float nb = -100.0f * norm8(B0, B1);
    const float nc = -100.0f * norm8(C0, C1);
    const float nd = -100.0f * norm8(D0, D1);

    const float4* lz4 = (const float4*)lz;
#pragma unroll 2
    for (int n = 0; n < 128; ++n) {
        float4 v0 = lz4[2 * n], v1 = lz4[2 * n + 1];   // broadcast
        float thr = lthr[n];
        float f0 = dotv(v0, v1, A0, A1, na);
        float f1 = dotv(v0, v1, B0, B1, nb);
        float f2 = dotv(v0, v1, C0, C1, nc);
        float f3 = dotv(v0, v1, D0, D1, nd);
        bool h0 = f0 > thr, h1 = f1 > thr, h2 = f2 > thr, h3 = f3 > thr;
        if (__any(h0 || h1 || h2 || h3)) {              // rare
            int row = row0 + n;
            if (h0) {
                int pos = atomicAdd(&gcnt[row], 1);
                if (pos < ROWCAP)
                    grec[row * ROWCAP + pos] = make_float2(f0, __int_as_float(k0));
            }
            if (h1) {
                int pos = atomicAdd(&gcnt[row], 1);
                if (pos < ROWCAP)
                    grec[row * ROWCAP + pos] = make_float2(f1, __int_as_float(k0 + 256));
            }
            if (h2) {
                int pos = atomicAdd(&gcnt[row], 1);
                if (pos < ROWCAP)
                    grec[row * ROWCAP + pos] = make_float2(f2, __int_as_float(k0 + 512));
            }
            if (h3) {
                int pos = atomicAdd(&gcnt[row], 1);
                if (pos < ROWCAP)
                    grec[row * ROWCAP + pos] = make_float2(f3, __int_as_float(k0 + 768));
            }
        }
    }
}

// ---------------- rowfix: 1 wave/row fast path; overflow -> list ----------
__global__ __launch_bounds__(256) void rowfix(
    const float* __restrict__ z, const float* __restrict__ cb,
    const int* __restrict__ gcnt, const float2* __restrict__ grec,
    float* __restrict__ avgp, float* __restrict__ out_zq,
    float* __restrict__ out_idx, float* __restrict__ scal,
    int* __restrict__ olcnt, int* __restrict__ olist)
{
    const int wave = threadIdx.x >> 6;
    const int lane = threadIdx.x & 63;
    const int row = blockIdx.x * 4 + wave;
    const float4* cbv = (const float4*)cb;
    const int c = gcnt[row];
    const int bbr = row >> 8, hw = row & 255;

    float ent = 0.0f, sq = 0.0f;
    if (c <= ROWCAP) {
        float f = -3.4e38f; int k = 0x7fffffff;
        if (lane < c) {
            float2 rc = grec[row * ROWCAP + lane];   // coalesced
            f = rc.x; k = __float_as_int(rc.y);
        }
        float m = f;
#pragma unroll
        for (int off = 32; off; off >>= 1) m = fmaxf(m, __shfl_xor(m, off));
        float x = f - m;
        float e = 0.0f, t = 0.0f;
        int kmin = 0x7fffffff;
        if (lane < c) {
            e = __expf(x);            // x > -87 guaranteed (thr = m-87)
            t = x * e;
            if (x == 0.0f) kmin = k;
        }
        float s = e;
#pragma unroll
        for (int off = 32; off; off >>= 1) {
            s += __shfl_xor(s, off);
            t += __shfl_xor(t, off);
            kmin = min(kmin, __shfl_xor(kmin, off));
        }
        float rs = 1.0f / s;
        if (e != 0.0f) atomicAdd(&avgp[k], e * rs);
        if (lane == 0) {
            ent = t * rs - logf(s);
            out_idx[row] = (float)kmin;
            float4 q0 = cbv[2 * kmin], q1 = cbv[2 * kmin + 1];
            float qv[8] = {q0.x, q0.y, q0.z, q0.w, q1.x, q1.y, q1.z, q1.w};
            const float* zp = z + bbr * 2048 + hw;
            float* o = out_zq + bbr * 2048 + hw;
#pragma unroll
            for (int ch = 0; ch < 8; ++ch) {
                float raw = zp[ch * 256];
                o[ch * 256] = qv[ch];
                float dq = qv[ch] - raw;
                sq += dq * dq;
            }
        }
    } else if (lane == 0) {
        int p = atomicAdd(olcnt, 1);
        olist[p] = row;               // handled by ovflow kernel
    }
    __shared__ float redSq[4], redEnt[4];
    if (lane == 0) { redSq[wave] = sq; redEnt[wave] = ent; }
    __syncthreads();
    if (threadIdx.x == 0) {
        atomicAdd(&scal[0], redSq[0] + redSq[1] + redSq[2] + redSq[3]);
        atomicAdd(&scal[1], redEnt[0] + redEnt[1] + redEnt[2] + redEnt[3]);
    }
}

// ---------------- ovflow: block-cooperative exact recompute ----------------
// 64 blocks; each handles overflow rows [b::64] from the compacted list.
__global__ __launch_bounds__(256) void ovflow(
    const float* __restrict__ z, const float* __restrict__ cb,
    const float* __restrict__ bkg, const int* __restrict__ olcnt,
    const int* __restrict__ olist, float* __restrict__ avgp,
    float* __restrict__ out_zq, float* __restrict__ out_idx,
    float* __restrict__ scal)
{
    const int nov = *olcnt;
    const int tid = threadIdx.x;
    const int wave = tid >> 6, lane = tid & 63;
    const float4* cbv = (const float4*)cb;
    __shared__ float4 mrg[4];
    __shared__ float  zsh[8];

    for (int i = blockIdx.x; i < nov; i += 64) {
        const int row = olist[i];
        const int bbr = row >> 8, hw = row & 255;
        if (tid < 8) zsh[tid] = z[bbr * 2048 + tid * 256 + hw];
        __syncthreads();
        float zs[8];
#pragma unroll
        for (int c = 0; c < 8; ++c) zs[c] = 200.0f * zsh[c];

        // per-thread online over k = j*256 + tid (64 independent iters)
        float m = -3.4e38f, s = 0.0f, t = 0.0f;
        int kmx = 0x7fffffff;
        for (int j = 0; j < 64; ++j) {
            int k = j * 256 + tid;
            float f = dot8v(zs, cbv[2 * k], cbv[2 * k + 1], bkg[k]);
            float x = f - m;
            if (x > 0.0f) {
                float fsc = __expf(-x);
                t = fsc * fmaf(-x, s, t);
                s = fmaf(s, fsc, 1.0f);
                m = f; kmx = k;
            } else if (x > -87.0f) {
                float e = __expf(x);
                s += e; t = fmaf(x, e, t);
            }
        }
        // wave butterfly merge
        for (int off = 32; off; off >>= 1) {
            float mo = __shfl_xor(m, off);
            float so = __shfl_xor(s, off);
            float to = __shfl_xor(t, off);
            int   ko = __shfl_xor(kmx, off);
            float mn = fmaxf(m, mo);
            float d1 = m - mn, d2 = mo - mn;
            float f1 = __expf(d1), f2 = __expf(d2);
            t = f1 * fmaf(d1, s, t) + f2 * fmaf(d2, so, to);
            s = f1 * s + f2 * so;
            kmx = (m > mo) ? kmx : ((mo > m) ? ko : (kmx < ko ? kmx : ko));
            m = mn;
        }
        if (lane == 0) mrg[wave] = make_float4(m, s, t, __int_as_float(kmx));
        __syncthreads();
        // every thread merges the 4 wave states (cheap, uniform)
        float M = -3.4e38f, S = 0.0f, T = 0.0f; int KM = 0x7fffffff;
#pragma unroll
        for (int w = 0; w < 4; ++w) {
            float4 q = mrg[w];
            float m2 = q.x, s2 = q.y, t2 = q.z; int k2 = __int_as_float(0), kk;
            kk = __float_as_int(q.w); k2 = kk;
            float mn = fmaxf(M, m2);
            float d1 = M - mn, d2 = m2 - mn;
            float f1 = __expf(d1), f2 = __expf(d2);
            T = f1 * fmaf(d1, S, T) + f2 * fmaf(d2, s2, t2);
            S = f1 * S + f2 * s2;
            KM = (M > m2) ? KM : ((m2 > M) ? k2 : (KM < k2 ? KM : k2));
            M = mn;
        }
        // streaming avgp pass
        float rs = 1.0f / S;
        for (int j = 0; j < 64; ++j) {
            int k = j * 256 + tid;
            float f = dot8v(zs, cbv[2 * k], cbv[2 * k + 1], bkg[k]);
            float x = f - M;
            if (x > -87.0f) atomicAdd(&avgp[k], __expf(x) * rs);
        }
        if (tid == 0) {
            out_idx[row] = (float)KM;
            float4 q0 = cbv[2 * KM], q1 = cbv[2 * KM + 1];
            float qv[8] = {q0.x, q0.y, q0.z, q0.w, q1.x, q1.y, q1.z, q1.w};
            float* o = out_zq + bbr * 2048 + hw;
            float sq = 0.0f;
#pragma unroll
            for (int ch = 0; ch < 8; ++ch) {
                o[ch * 256] = qv[ch];
                float dq = qv[ch] - zsh[ch];
                sq += dq * dq;
            }
            atomicAdd(&scal[0], sq);
            atomicAdd(&scal[1], T * rs - logf(S));
        }
        __syncthreads();   // zsh/mrg reuse
    }
}

// ---------------- finalize: avg entropy + loss assembly ----------------
__global__ __launch_bounds__(256) void finalize(
    const float* __restrict__ avgp, const float* __restrict__ scal,
    float* __restrict__ out_loss)
{
    float acc = 0.0f;
    for (int k = threadIdx.x; k < KCODES; k += 256) {
        float avg = avgp[k] * (1.0f / 8192.0f);
        acc += avg * logf(avg + 1e-5f);    // avg==0 contributes exactly 0
    }
#pragma unroll
    for (int off = 32; off > 0; off >>= 1) acc += __shfl_xor(acc, off);
    __shared__ float red[4];
    int wave = threadIdx.x >> 6, lane = threadIdx.x & 63;
    if (lane == 0) red[wave] = acc;
    __syncthreads();
    if (threadIdx.x == 0) {
        float T = red[0] + red[1] + red[2] + red[3];   // sum avg*log(avg+eps)
        float loss = 1.25f * (scal[0] * (1.0f / 65536.0f))
                   + 0.1f * (T - scal[1] * (1.0f / 8192.0f));
        out_loss[0] = loss;
    }
}

extern "C" void kernel_launch(void* const* d_in, const int* in_sizes, int n_in,
                              void* d_out, int out_size, void* d_ws, size_t ws_size,
                              hipStream_t stream) {
    const float* z  = (const float*)d_in[0];   // [32,8,16,16]
    const float* cb = (const float*)d_in[1];   // [16384,8]
    float* out = (float*)d_out;
    float* ws  = (float*)d_ws;

    // workspace layout (floats)
    float*  avgp = ws;                        // 16384
    float*  scal = ws + 16384;                // 2 (+6 pad)
    int*    gcnt = (int*)(ws + 16392);        // 8192
    int*    olcnt= (int*)(ws + 24584);        // 1 (+7 pad)
    int*    olist= (int*)(ws + 24592);        // 8192
    int*    rmax = (int*)(ws + 32784);        // 8192
    float*  bkg  = ws + 40976;                // 16384
    float2* grec = (float2*)(ws + 57360);     // 8192*64 float2 = 4 MB

    float* out_zq   = out;           // 65536
    float* out_loss = out + 65536;   // 1
    float* out_idx  = out + 65537;   // 8192

    // zero avgp/scal/gcnt/olcnt; rowmax <- encoded -3.4e38
    hipMemsetAsync(ws, 0, (16384 + 8 + 8192 + 8) * sizeof(float), stream);
    hipMemsetAsync(rmax, 0x80, 8192 * sizeof(int), stream);

    prep_cb <<<64,   256, 0, stream>>>(cb, bkg);
    maxpass <<<1024, 256, 0, stream>>>(z, cb, bkg, rmax);
    candpass<<<1024, 256, 0, stream>>>(z, cb, rmax, gcnt, grec);
    rowfix  <<<2048, 256, 0, stream>>>(z, cb, gcnt, grec, avgp, out_zq,
                                       out_idx, scal, olcnt, olist);
    ovflow  <<<64,   256, 0, stream>>>(z, cb, bkg, olcnt, olist, avgp,
                                       out_zq, out_idx, scal);
    finalize<<<1,    256, 0, stream>>>(avgp, scal, out_loss);
}